// Round 4
// baseline (192.327 us; speedup 1.0000x reference)
//
#include <hip/hip_runtime.h>
#include <stdint.h>

// Problem constants (from reference): B=2, S=4096, D_MODEL=1024, H=16, d_k=64
// RADIUS = ceil(sqrt(4*0.28*ln(1e6))*2) = 8, window = 9 (positions s-8..s)
constexpr int S_LEN = 4096;
constexpr int DM    = 1024;
constexpr int RAD   = 8;
constexpr int NQKV  = 3072;   // fused QKV output width (row stride of QKVh)
constexpr float INV2T = 1.7857142857142858f; // 1/(2*0.28)

typedef _Float16 h8v __attribute__((ext_vector_type(8)));  // 8 f16 (4 VGPRs) MFMA frag
typedef float f32x4  __attribute__((ext_vector_type(4)));  // MFMA accumulator

// async global->LDS, 16B/lane. LDS dst is wave-uniform base + lane*16 (HW rule).
static __device__ __forceinline__ void gl_lds16(const void* gp, void* lp) {
  auto g = (const __attribute__((address_space(1))) void*)(uintptr_t)gp;
  auto l = (__attribute__((address_space(3))) void*)(uint32_t)(uintptr_t)lp;
  __builtin_amdgcn_global_load_lds(g, l, 16, 0, 0);
}

// ---------------- prep: x->fp16 cast + 4x W transpose-cast, one launch -------
__global__ __launch_bounds__(256) void sda_prep_kernel(
    const float* __restrict__ X, _Float16* __restrict__ XH,
    const float* __restrict__ W0, const float* __restrict__ W1,
    const float* __restrict__ W2, const float* __restrict__ W3,
    _Float16* __restrict__ T0, _Float16* __restrict__ T1,
    _Float16* __restrict__ T2, _Float16* __restrict__ T3) {
  __shared__ float t[32][33];
  int z = blockIdx.z;
  int tx = threadIdx.x, ty = threadIdx.y;
  if (z < 4) {
    const float* W = z == 0 ? W0 : (z == 1 ? W1 : (z == 2 ? W2 : W3));
    _Float16*    T = z == 0 ? T0 : (z == 1 ? T1 : (z == 2 ? T2 : T3));
    int n0 = blockIdx.x * 32, k0 = blockIdx.y * 32;
#pragma unroll
    for (int i = 0; i < 4; ++i)
      t[ty + 8 * i][tx] = W[(size_t)(k0 + ty + 8 * i) * DM + n0 + tx];
    __syncthreads();
#pragma unroll
    for (int i = 0; i < 4; ++i)
      T[(size_t)(n0 + ty + 8 * i) * DM + k0 + tx] = (_Float16)t[tx][ty + 8 * i];
  } else {
    int blk = (z - 4) * 1024 + blockIdx.y * 32 + blockIdx.x;
    int i = blk * 256 + ty * 32 + tx;
    const float4* x4 = (const float4*)X;
    float4 a = x4[2 * i], b = x4[2 * i + 1];
    float f[8] = {a.x, a.y, a.z, a.w, b.x, b.y, b.z, b.w};
    union { _Float16 h[8]; uint4 v; } o;
#pragma unroll
    for (int j = 0; j < 8; ++j) o.h[j] = (_Float16)f[j];
    ((uint4*)XH)[i] = o.v;
  }
}

// ------- QKV GEMM: 8-phase-style counted-vmcnt pipeline (T3+T4+T5) ----------
// BM=256, BN=192, BK=64, 512 thr = 8 waves (2M x 4N), per-wave 128x48.
// 2 LDS buffers (112 KB). 4 phases per K-tile, 12 MFMA each:
//   [7 ds_read_b128][gl_lds issues][vmcnt gate][s_barrier][setprio 12xMFMA][s_barrier]
// Staging of tile t+1: {A0,A1,B0,B1,B2} at p0, {A2,A3} at p1.
// Gates: vmcnt(5) at p0 (confirms prev A2,A3), vmcnt(2) at p3 (confirms
// next tile's first 5) -- never 0 in steady state; every awaited load has
// been in flight >=3 phases. Grid 32x16 = 512 blocks = exactly 2 CU-rounds.
// XOR-chunk LDS swizzle + K-accumulation order identical to verified R6.
__global__ __launch_bounds__(512, 2) void sda_gemm_qkv_pipe(
    const _Float16* __restrict__ A, const _Float16* __restrict__ Bt,
    _Float16* __restrict__ C) {
  constexpr int Kd = DM;
  constexpr int NT = Kd / 64;   // 16 K-tiles
  __shared__ __align__(16) _Float16 As[2][256 * 64];  // 64 KB
  __shared__ __align__(16) _Float16 Bs[2][192 * 64];  // 48 KB => 112 KB

  int blk = blockIdx.x;
  int xcd = blk & 7, slot = blk >> 3;   // 64 slots per XCD
  int xt = slot & 15, yq = slot >> 4;   // x-major: A-stripe stays hot in XCD L2
  int yt = (xcd << 2) | yq;             // yt in [0,32)
  int m0 = yt * 256, n0 = xt * 192;

  int tid = threadIdx.x, wid = tid >> 6, lane = tid & 63;
  int srow = lane >> 3;
  int sgk = ((lane & 7) ^ srow) * 8;    // XOR-permuted global k-chunk (T2)
  int wm = (wid >> 2) * 128, wn = (wid & 3) * 48;
  int fm = lane & 15, fc = lane >> 4;

  // staging bases: sweep s covers rows [64s,64s+64); wave w stages rows
  // [64s+8w, 64s+8w+8), lane l -> row +(l>>3), chunk (l&7) -> linear LDS.
  const _Float16* Ar = A  + (size_t)(m0 + 8 * wid + srow) * Kd + sgk;
  const _Float16* Br = Bt + (size_t)(n0 + 8 * wid + srow) * Kd + sgk;

  f32x4 acc[8][3] = {};   // 96 VGPRs

#define STA(buf, kt, s) \
  gl_lds16(Ar + (size_t)(64 * (s)) * Kd + (kt) * 64, &As[buf][(64 * (s) + 8 * wid) * 64])
#define STB(buf, kt, s) \
  gl_lds16(Br + (size_t)(64 * (s)) * Kd + (kt) * 64, &Bs[buf][(64 * (s) + 8 * wid) * 64])

#define LDA4(af, cbuf, mh, ks)                                              \
  _Pragma("unroll") for (int i = 0; i < 4; ++i) {                           \
    int row = wm + (mh) * 64 + i * 16 + fm;                                 \
    af[i] = *(const h8v*)&As[cbuf][row * 64 + ((((ks) * 4 + fc) ^ (row & 7)) * 8)]; \
  }
#define LDB3(bf, cbuf, ks)                                                  \
  _Pragma("unroll") for (int j = 0; j < 3; ++j) {                           \
    int row = wn + j * 16 + fm;                                             \
    bf[j] = *(const h8v*)&Bs[cbuf][row * 64 + ((((ks) * 4 + fc) ^ (row & 7)) * 8)]; \
  }
#define MFMA12(af, bf, mh)                                                  \
  __builtin_amdgcn_s_setprio(1);                                            \
  _Pragma("unroll") for (int i = 0; i < 4; ++i)                             \
  _Pragma("unroll") for (int j = 0; j < 3; ++j)                             \
    acc[(mh) * 4 + i][j] =                                                  \
        __builtin_amdgcn_mfma_f32_16x16x32_f16(af[i], bf[j], acc[(mh) * 4 + i][j], 0, 0, 0); \
  __builtin_amdgcn_s_setprio(0);
#define BARRIER asm volatile("s_barrier" ::: "memory")

  // prologue: S_0 in issue order [A0,A1,B0,B1,B2 | A2,A3]; gate first 5.
  STA(0, 0, 0); STA(0, 0, 1); STB(0, 0, 0); STB(0, 0, 1); STB(0, 0, 2);
  STA(0, 0, 2); STA(0, 0, 3);
  asm volatile("s_waitcnt vmcnt(2)" ::: "memory");
  BARRIER;

#pragma unroll 1
  for (int t = 0; t < NT; ++t) {
    int c = t & 1, nb = c ^ 1;
    bool pre = (t + 1 < NT);
    { // phase 0: compute (mh0, ks0); stage next tile's first 5 sweeps
      h8v af[4], bf[3];
      LDA4(af, c, 0, 0); LDB3(bf, c, 0);
      if (pre) {
        STA(nb, t + 1, 0); STA(nb, t + 1, 1);
        STB(nb, t + 1, 0); STB(nb, t + 1, 1); STB(nb, t + 1, 2);
        asm volatile("s_waitcnt vmcnt(5)" ::: "memory");   // prev A2,A3 done
      } else {
        asm volatile("s_waitcnt vmcnt(0)" ::: "memory");   // last tile drain
      }
      BARRIER;
      MFMA12(af, bf, 0);
      BARRIER;
    }
    { // phase 1: (mh1, ks0); stage next tile's A2,A3
      h8v af[4], bf[3];
      LDA4(af, c, 1, 0); LDB3(bf, c, 0);
      if (pre) { STA(nb, t + 1, 2); STA(nb, t + 1, 3); }
      BARRIER;
      MFMA12(af, bf, 1);
      BARRIER;
    }
    { // phase 2: (mh0, ks1)
      h8v af[4], bf[3];
      LDA4(af, c, 0, 1); LDB3(bf, c, 1);
      BARRIER;
      MFMA12(af, bf, 0);
      BARRIER;
    }
    { // phase 3: (mh1, ks1); gate next tile's first 5 (A2,A3 stay in flight)
      h8v af[4], bf[3];
      LDA4(af, c, 1, 1); LDB3(bf, c, 1);
      if (pre) asm volatile("s_waitcnt vmcnt(2)" ::: "memory");
      BARRIER;
      MFMA12(af, bf, 1);
      BARRIER;
    }
  }

  int rr = (lane >> 4) * 4, cc = lane & 15;
#pragma unroll
  for (int i = 0; i < 8; ++i)
#pragma unroll
    for (int j = 0; j < 3; ++j) {
      size_t base = (size_t)(m0 + wm + i * 16 + rr) * NQKV + (n0 + wn + j * 16 + cc);
#pragma unroll
      for (int r = 0; r < 4; ++r)
        C[base + (size_t)r * NQKV] = (_Float16)acc[i][j][r];
    }
#undef STA
#undef STB
#undef LDA4
#undef LDB3
#undef MFMA12
#undef BARRIER
}

// ------- Wo GEMM: proven R6 128x128 structure (512 blocks, ~4 blocks/CU) ----
__global__ __launch_bounds__(256) void sda_gemm_wo_kernel(
    const _Float16* __restrict__ A, const _Float16* __restrict__ Bt,
    float* __restrict__ C) {
  constexpr int Kd = DM;
  constexpr int BM = 128, BN = 128, BK = 64;
  __shared__ __align__(16) _Float16 As[BM * BK];
  __shared__ __align__(16) _Float16 Bs[BN * BK];

  int blk = blockIdx.x;
  int xcd = blk & 7, slot = blk >> 3;   // 64 slots/XCD
  int xt = slot >> 3, ys = slot & 7;    // 8 x-tiles, x-major
  int yt = (xcd << 3) | ys;
  int m0 = yt * BM, n0 = xt * BN;

  int tid = threadIdx.x, wid = tid >> 6, lane = tid & 63;
  int srow = lane >> 3;
  int sgk = ((lane & 7) ^ (srow & 7)) * 8;
  int wm = (wid >> 1) * 64, wn = (wid & 1) * 64;
  int fm = lane & 15, fc = lane >> 4;

  f32x4 acc[4][4] = {};

  for (int kt = 0; kt < Kd / BK; ++kt) {
    if (kt) __syncthreads();
    int kk = kt * BK;
    int r0 = wid * 32;
#pragma unroll
    for (int i = 0; i < 4; ++i) {
      gl_lds16(A  + (size_t)(m0 + r0 + i * 8 + srow) * Kd + kk + sgk, &As[(r0 + i * 8) * BK]);
      gl_lds16(Bt + (size_t)(n0 + r0 + i * 8 + srow) * Kd + kk + sgk, &Bs[(r0 + i * 8) * BK]);
    }
    __syncthreads();

#pragma unroll
    for (int ks = 0; ks < 2; ++ks) {
      h8v af[4], bfr[4];
#pragma unroll
      for (int i = 0; i < 4; ++i) {
        int row = wm + i * 16 + fm;
        af[i] = *(const h8v*)&As[row * BK + (((ks * 4 + fc) ^ (row & 7)) * 8)];
      }
#pragma unroll
      for (int j = 0; j < 4; ++j) {
        int row = wn + j * 16 + fm;
        bfr[j] = *(const h8v*)&Bs[row * BK + (((ks * 4 + fc) ^ (row & 7)) * 8)];
      }
#pragma unroll
      for (int i = 0; i < 4; ++i)
#pragma unroll
        for (int j = 0; j < 4; ++j)
          acc[i][j] = __builtin_amdgcn_mfma_f32_16x16x32_f16(af[i], bfr[j], acc[i][j], 0, 0, 0);
    }
  }

  int rr = (lane >> 4) * 4, cc = lane & 15;
#pragma unroll
  for (int i = 0; i < 4; ++i)
#pragma unroll
    for (int j = 0; j < 4; ++j) {
      size_t base = (size_t)(m0 + wm + i * 16 + rr) * DM + (n0 + wn + j * 16 + cc);
#pragma unroll
      for (int r = 0; r < 4; ++r)
        C[base + (size_t)r * DM] = acc[i][j][r];
    }
}

// ---------------- BARRIER-FREE per-wave windowed attention ----------------
// Q/K/V now live in the fused QKVh buffer: row stride NQKV=3072, with K at
// col offset +1024 and V at +2048 (passed as pre-offset pointers).
// Output O (Ah) keeps row stride DM=1024. Structure otherwise unchanged
// (R6-verified): per-wave LDS slices, zero __syncthreads, odd-dword strides.
__global__ __launch_bounds__(256) void sda_attn_kernel(
    const _Float16* __restrict__ Q, const _Float16* __restrict__ K,
    const _Float16* __restrict__ V, _Float16* __restrict__ O) {
  constexpr int KS  = 72;  // kw row stride f16: 144B = 36 dw
  constexpr int VTS = 40;  // vt row stride f16: 80B = 20 dw
  constexpr int WS  = 40;  // wt row stride f16
  __shared__ __align__(16) _Float16 kw[4][32 * KS];   // 4.5 KB/wave
  __shared__ __align__(16) _Float16 vt[4][64 * VTS];  // 5 KB/wave [dim][key]
  __shared__ __align__(16) float    sc[4][16 * 33];   // 2.06 KB/wave
  __shared__ __align__(16) _Float16 wt[4][16 * WS];   // 1.25 KB/wave => 52.5 KB total

  int bh = blockIdx.y, b = bh >> 4, h = bh & 15;
  int s0 = blockIdx.x * 64;
  int tid = threadIdx.x, wid = tid >> 6, lane = tid & 63;
  size_t qkvoff = (size_t)b * S_LEN * NQKV + h * 64;  // Q/K/V (stride 3072)
  size_t ooff   = (size_t)b * S_LEN * DM   + h * 64;  // O (stride 1024)

  _Float16* kwp = kw[wid];
  _Float16* vtp = vt[wid];
  float*    scp = sc[wid];
  _Float16* wtp = wt[wid];

  int p0 = s0 + wid * 16 - RAD;    // first key pos of this wave's 24-key band
  int fm = lane & 15, fkg = (lane >> 4) * 8;
  int rr = (lane >> 4) * 4, cc = lane & 15;

  // zero wt fully (1280 B = 80 x 16B) and vt key-cols 24..31 (0*NaN guard)
  {
    uint4 z = make_uint4(0, 0, 0, 0);
    ((uint4*)wtp)[lane] = z;
    if (lane < 16) ((uint4*)wtp)[64 + lane] = z;
    *(uint4*)&vtp[lane * VTS + 24] = z;
  }

  // stage K rows 0..23 row-major (24 x 8 chunks = 192 items, 3/lane)
#pragma unroll
  for (int i = 0; i < 3; ++i) {
    int item = i * 64 + lane;
    int row = item >> 3, ch = (item & 7) * 8;
    int pos = p0 + row;
    uint4 kv = make_uint4(0, 0, 0, 0);
    if (pos >= 0) kv = *(const uint4*)(K + qkvoff + (size_t)pos * NQKV + ch);
    *(uint4*)&kwp[row * KS + ch] = kv;
  }
  // stage V transposed: vt[dim][key]
#pragma unroll
  for (int i = 0; i < 3; ++i) {
    int item = i * 64 + lane;
    int row = item >> 3, chb = (item & 7) * 8;
    int pos = p0 + row;
    uint4 vv = make_uint4(0, 0, 0, 0);
    if (pos >= 0) vv = *(const uint4*)(V + qkvoff + (size_t)pos * NQKV + chb);
    union { uint4 v; _Float16 hh[8]; } u; u.v = vv;
#pragma unroll
    for (int d = 0; d < 8; ++d) vtp[(chb + d) * VTS + row] = u.hh[d];
  }

  // Q fragments straight from global (rows always valid)
  const _Float16* qrow = Q + qkvoff + (size_t)(s0 + wid * 16 + fm) * NQKV;
  h8v aq0 = *(const h8v*)(qrow + fkg);
  h8v aq1 = *(const h8v*)(qrow + 32 + fkg);

  // ---- QK^T: 2 local key-tiles x K=64 ----
  f32x4 accs[2] = {};
#pragma unroll
  for (int t = 0; t < 2; ++t) {
    h8v bk0 = *(const h8v*)&kwp[(t * 16 + fm) * KS + fkg];
    h8v bk1 = *(const h8v*)&kwp[(t * 16 + fm) * KS + 32 + fkg];
    accs[t] = __builtin_amdgcn_mfma_f32_16x16x32_f16(aq0, bk0, accs[t], 0, 0, 0);
    accs[t] = __builtin_amdgcn_mfma_f32_16x16x32_f16(aq1, bk1, accs[t], 0, 0, 0);
  }
#pragma unroll
  for (int t = 0; t < 2; ++t)
#pragma unroll
    for (int r = 0; r < 4; ++r)
      scp[(rr + r) * 33 + t * 16 + cc] = accs[t][r];

  // ---- softmax: lane r (0..15) owns q-row r; band cols r..r+8 (< 24) ----
  if (lane < 16) {
    int r = lane, s = s0 + wid * 16 + r;
    const float* my = &scp[r * 33 + r];
    float e[9], mx = -1e30f;
#pragma unroll
    for (int j = 0; j < 9; ++j) {
      float p = my[j] * INV2T;
      e[j] = (s - RAD + j >= 0) ? p : -1e30f;
      mx = fmaxf(mx, e[j]);
    }
    float se = 0.f;
#pragma unroll
    for (int j = 0; j < 9; ++j) { e[j] = __expf(e[j] - mx); se += e[j]; }
    float inv = 1.f / se;
#pragma unroll
    for (int j = 0; j < 9; ++j)
      wtp[r * WS + r + j] = (_Float16)(e[j] * inv);
  }

  // ---- PV: O(16x64) = wt(16x32) @ V(32x64); one K=32 MFMA per n-tile ----
  f32x4 acco[4] = {};
  h8v aw = *(const h8v*)&wtp[fm * WS + fkg];
#pragma unroll
  for (int t = 0; t < 4; ++t) {
    h8v bv = *(const h8v*)&vtp[(t * 16 + fm) * VTS + fkg];
    acco[t] = __builtin_amdgcn_mfma_f32_16x16x32_f16(aw, bv, acco[t], 0, 0, 0);
  }
#pragma unroll
  for (int t = 0; t < 4; ++t)
#pragma unroll
    for (int r = 0; r < 4; ++r)
      O[ooff + (size_t)(s0 + wid * 16 + rr + r) * DM + t * 16 + cc] =
          (_Float16)acco[t][r];
}

extern "C" void kernel_launch(void* const* d_in, const int* in_sizes, int n_in,
                              void* d_out, int out_size, void* d_ws, size_t ws_size,
                              hipStream_t stream) {
  (void)in_sizes; (void)n_in; (void)out_size; (void)ws_size;
  const float* x  = (const float*)d_in[0];
  const float* Wq = (const float*)d_in[1];
  const float* Wk = (const float*)d_in[2];
  const float* Wv = (const float*)d_in[3];
  const float* Wo = (const float*)d_in[4];

  char* ws = (char*)d_ws;
  const size_t MB = 1ull << 20;
  _Float16* xh    = (_Float16*)(ws + 0);        // 16 MB
  _Float16* WqkvT = (_Float16*)(ws + 16 * MB);  // 6 MB: Wq^T|Wk^T|Wv^T (= [3072][1024])
  _Float16* WoT   = (_Float16*)(ws + 22 * MB);  // 2 MB
  _Float16* QKVh  = (_Float16*)(ws + 24 * MB);  // 48 MB fused [8192][3072]
  _Float16* Ah    = (_Float16*)(ws + 72 * MB);  // 16 MB => total 88 MB

  sda_prep_kernel<<<dim3(32, 32, 8), dim3(32, 8), 0, stream>>>(
      x, xh, Wq, Wk, Wv, Wo,
      WqkvT, WqkvT + (size_t)DM * DM, WqkvT + 2ull * DM * DM, WoT);

  // QKV fused: M=8192, N=3072, BM=256 x BN=192 -> 512 blocks = 2 CU-rounds
  sda_gemm_qkv_pipe<<<512, 512, 0, stream>>>(xh, WqkvT, QKVh);
  sda_attn_kernel<<<dim3(64, 32), 256, 0, stream>>>(
      QKVh, QKVh + 1024, QKVh + 2048, Ah);
  // Wo: 128x128 -> 512 blocks
  sda_gemm_wo_kernel<<<512, 256, 0, stream>>>(Ah, WoT, (float*)d_out);
}

// Round 5
// 181.866 us; speedup vs baseline: 1.0575x; 1.0575x over previous
//
#include <hip/hip_runtime.h>
#include <stdint.h>

// Problem constants (from reference): B=2, S=4096, D_MODEL=1024, H=16, d_k=64
// RADIUS = ceil(sqrt(4*0.28*ln(1e6))*2) = 8, window = 9 (positions s-8..s)
constexpr int S_LEN = 4096;
constexpr int DM    = 1024;
constexpr int RAD   = 8;
constexpr float INV2T = 1.7857142857142858f; // 1/(2*0.28)

constexpr int BM = 128, BN = 128, BK = 64;   // BK=64: 32 MFMA/barrier (measured: 31.5->38% MfmaUtil)

typedef _Float16 h8v __attribute__((ext_vector_type(8)));  // 8 f16 (4 VGPRs) MFMA frag
typedef float f32x4  __attribute__((ext_vector_type(4)));  // MFMA accumulator

// async global->LDS, 16B/lane. LDS dst is wave-uniform base + lane*16 (HW rule).
static __device__ __forceinline__ void gl_lds16(const void* gp, void* lp) {
  auto g = (const __attribute__((address_space(1))) void*)(uintptr_t)gp;
  auto l = (__attribute__((address_space(3))) void*)(uint32_t)(uintptr_t)lp;
  __builtin_amdgcn_global_load_lds(g, l, 16, 0, 0);
}

// ---------------- prep: x->fp16 cast + 4x W transpose-cast, one launch -------
__global__ __launch_bounds__(256) void sda_prep_kernel(
    const float* __restrict__ X, _Float16* __restrict__ XH,
    const float* __restrict__ W0, const float* __restrict__ W1,
    const float* __restrict__ W2, const float* __restrict__ W3,
    _Float16* __restrict__ T0, _Float16* __restrict__ T1,
    _Float16* __restrict__ T2, _Float16* __restrict__ T3) {
  __shared__ float t[32][33];
  int z = blockIdx.z;
  int tx = threadIdx.x, ty = threadIdx.y;
  if (z < 4) {
    const float* W = z == 0 ? W0 : (z == 1 ? W1 : (z == 2 ? W2 : W3));
    _Float16*    T = z == 0 ? T0 : (z == 1 ? T1 : (z == 2 ? T2 : T3));
    int n0 = blockIdx.x * 32, k0 = blockIdx.y * 32;
#pragma unroll
    for (int i = 0; i < 4; ++i)
      t[ty + 8 * i][tx] = W[(size_t)(k0 + ty + 8 * i) * DM + n0 + tx];
    __syncthreads();
#pragma unroll
    for (int i = 0; i < 4; ++i)
      T[(size_t)(n0 + ty + 8 * i) * DM + k0 + tx] = (_Float16)t[tx][ty + 8 * i];
  } else {
    int blk = (z - 4) * 1024 + blockIdx.y * 32 + blockIdx.x;
    int i = blk * 256 + ty * 32 + tx;
    const float4* x4 = (const float4*)X;
    float4 a = x4[2 * i], b = x4[2 * i + 1];
    float f[8] = {a.x, a.y, a.z, a.w, b.x, b.y, b.z, b.w};
    union { _Float16 h[8]; uint4 v; } o;
#pragma unroll
    for (int j = 0; j < 8; ++j) o.h[j] = (_Float16)f[j];
    ((uint4*)XH)[i] = o.v;
  }
}

// ------- fp16 GEMM, XCD-swizzled, BK=64 (R6-verified: MfmaUtil 38%, conflicts 0) ----
__global__ __launch_bounds__(256) void sda_gemm_qkv_kernel(
    const _Float16* __restrict__ A, const _Float16* __restrict__ Bt,
    _Float16* __restrict__ C0, _Float16* __restrict__ C1,
    _Float16* __restrict__ C2) {
  constexpr int Kd = DM;
  __shared__ __align__(16) _Float16 As[BM * BK];  // 16 KB, 128B rows, chunk-XORed
  __shared__ __align__(16) _Float16 Bs[BN * BK];  // 16 KB

  int blk = blockIdx.x;
  int xcd = blk & 7, slot = blk >> 3;
  int xt = slot >> 3, ys = slot & 7;    // x-major within XCD
  int yt = (xcd << 3) | ys;             // y-stripe per XCD
  int m0 = yt * BM, n0 = xt * BN;

  int tid = threadIdx.x, wid = tid >> 6, lane = tid & 63;
  int srow = lane >> 3;
  int sgk = ((lane & 7) ^ (srow & 7)) * 8;    // XOR-permuted global k-chunk
  int wm = (wid >> 1) * 64, wn = (wid & 1) * 64;
  int fm = lane & 15, fc = lane >> 4;

  f32x4 acc[4][4] = {};

  for (int kt = 0; kt < Kd / BK; ++kt) {
    if (kt) __syncthreads();
    int kk = kt * BK;
    int r0 = wid * 32;
#pragma unroll
    for (int i = 0; i < 4; ++i) {
      gl_lds16(A  + (size_t)(m0 + r0 + i * 8 + srow) * Kd + kk + sgk, &As[(r0 + i * 8) * BK]);
      gl_lds16(Bt + (size_t)(n0 + r0 + i * 8 + srow) * Kd + kk + sgk, &Bs[(r0 + i * 8) * BK]);
    }
    __syncthreads();

#pragma unroll
    for (int ks = 0; ks < 2; ++ks) {
      h8v af[4], bfr[4];
#pragma unroll
      for (int i = 0; i < 4; ++i) {
        int row = wm + i * 16 + fm;
        af[i] = *(const h8v*)&As[row * BK + (((ks * 4 + fc) ^ (row & 7)) * 8)];
      }
#pragma unroll
      for (int j = 0; j < 4; ++j) {
        int row = wn + j * 16 + fm;
        bfr[j] = *(const h8v*)&Bs[row * BK + (((ks * 4 + fc) ^ (row & 7)) * 8)];
      }
#pragma unroll
      for (int i = 0; i < 4; ++i)
#pragma unroll
        for (int j = 0; j < 4; ++j)
          acc[i][j] = __builtin_amdgcn_mfma_f32_16x16x32_f16(af[i], bfr[j], acc[i][j], 0, 0, 0);
    }
  }

  int which = n0 >> 10, nc = n0 & 1023;
  _Float16* Cv = which == 0 ? C0 : (which == 1 ? C1 : C2);

  int rr = (lane >> 4) * 4, cc = lane & 15;
#pragma unroll
  for (int i = 0; i < 4; ++i)
#pragma unroll
    for (int j = 0; j < 4; ++j) {
      size_t base = (size_t)(m0 + wm + i * 16 + rr) * DM + (nc + wn + j * 16 + cc);
#pragma unroll
      for (int r = 0; r < 4; ++r)
        Cv[base + (size_t)r * DM] = (_Float16)acc[i][j][r];
    }
}

// ------- Wo GEMM: proven R6 128x128 structure (512 blocks, ~4 blocks/CU) ----
__global__ __launch_bounds__(256) void sda_gemm_wo_kernel(
    const _Float16* __restrict__ A, const _Float16* __restrict__ Bt,
    float* __restrict__ C) {
  constexpr int Kd = DM;
  __shared__ __align__(16) _Float16 As[BM * BK];
  __shared__ __align__(16) _Float16 Bs[BN * BK];

  int blk = blockIdx.x;
  int xcd = blk & 7, slot = blk >> 3;   // 64 slots/XCD
  int xt = slot >> 3, ys = slot & 7;    // 8 x-tiles, x-major
  int yt = (xcd << 3) | ys;
  int m0 = yt * BM, n0 = xt * BN;

  int tid = threadIdx.x, wid = tid >> 6, lane = tid & 63;
  int srow = lane >> 3;
  int sgk = ((lane & 7) ^ (srow & 7)) * 8;
  int wm = (wid >> 1) * 64, wn = (wid & 1) * 64;
  int fm = lane & 15, fc = lane >> 4;

  f32x4 acc[4][4] = {};

  for (int kt = 0; kt < Kd / BK; ++kt) {
    if (kt) __syncthreads();
    int kk = kt * BK;
    int r0 = wid * 32;
#pragma unroll
    for (int i = 0; i < 4; ++i) {
      gl_lds16(A  + (size_t)(m0 + r0 + i * 8 + srow) * Kd + kk + sgk, &As[(r0 + i * 8) * BK]);
      gl_lds16(Bt + (size_t)(n0 + r0 + i * 8 + srow) * Kd + kk + sgk, &Bs[(r0 + i * 8) * BK]);
    }
    __syncthreads();

#pragma unroll
    for (int ks = 0; ks < 2; ++ks) {
      h8v af[4], bfr[4];
#pragma unroll
      for (int i = 0; i < 4; ++i) {
        int row = wm + i * 16 + fm;
        af[i] = *(const h8v*)&As[row * BK + (((ks * 4 + fc) ^ (row & 7)) * 8)];
      }
#pragma unroll
      for (int j = 0; j < 4; ++j) {
        int row = wn + j * 16 + fm;
        bfr[j] = *(const h8v*)&Bs[row * BK + (((ks * 4 + fc) ^ (row & 7)) * 8)];
      }
#pragma unroll
      for (int i = 0; i < 4; ++i)
#pragma unroll
        for (int j = 0; j < 4; ++j)
          acc[i][j] = __builtin_amdgcn_mfma_f32_16x16x32_f16(af[i], bfr[j], acc[i][j], 0, 0, 0);
    }
  }

  int rr = (lane >> 4) * 4, cc = lane & 15;
#pragma unroll
  for (int i = 0; i < 4; ++i)
#pragma unroll
    for (int j = 0; j < 4; ++j) {
      size_t base = (size_t)(m0 + wm + i * 16 + rr) * DM + (n0 + wn + j * 16 + cc);
#pragma unroll
      for (int r = 0; r < 4; ++r)
        C[base + (size_t)r * DM] = acc[i][j][r];
    }
}

// ---------------- BARRIER-FREE per-wave windowed attention v2 ----------------
// Grid (S/64, B*H), 256 thr = 4 waves. Wave w owns q-rows [16w,16w+16).
// v2 change: K is NOT staged in LDS. The QK B-fragment is per-lane row
// p0+t*16+fm, 16B chunk fkg -- a direct global dwordx4 with the row index
// clamped to [0,S-1]. Clamped/garbage rows only feed score columns outside
// the banded window, which the softmax masks to weight 0 (and wt zeroing
// covers), so correctness is unchanged and no OOB access occurs.
// Removes per wave: 3 predicated uint4 loads + 3 ds_write_b128 + 4
// ds_read_b128 + one lgkm stall. LDS 52.5 -> 34 KB/block => 4 blocks/CU
// (16 waves) instead of 3 (12) for better latency hiding.
// V stays staged transposed (vt[dim][key]); strides odd-dword (80B) =>
// <=2-way bank aliasing (free, m136).
__global__ __launch_bounds__(256) void sda_attn_kernel(
    const _Float16* __restrict__ Q, const _Float16* __restrict__ K,
    const _Float16* __restrict__ V, _Float16* __restrict__ O) {
  constexpr int VTS = 40;  // vt row stride f16: 80B = 20 dw
  constexpr int WS  = 40;  // wt row stride f16
  __shared__ __align__(16) _Float16 vt[4][64 * VTS];  // 5 KB/wave [dim][key]
  __shared__ __align__(16) float    sc[4][16 * 33];   // 2.06 KB/wave
  __shared__ __align__(16) _Float16 wt[4][16 * WS];   // 1.25 KB/wave => 34 KB total

  int bh = blockIdx.y, b = bh >> 4, h = bh & 15;
  int s0 = blockIdx.x * 64;
  int tid = threadIdx.x, wid = tid >> 6, lane = tid & 63;
  size_t headoff = (size_t)b * S_LEN * DM + h * 64;

  _Float16* vtp = vt[wid];
  float*    scp = sc[wid];
  _Float16* wtp = wt[wid];

  int p0 = s0 + wid * 16 - RAD;    // first key pos of this wave's 24-key band
  int fm = lane & 15, fkg = (lane >> 4) * 8;
  int rr = (lane >> 4) * 4, cc = lane & 15;

  // zero wt fully (1280 B = 80 x 16B) and vt key-cols 24..31 (0*NaN guard)
  {
    uint4 z = make_uint4(0, 0, 0, 0);
    ((uint4*)wtp)[lane] = z;
    if (lane < 16) ((uint4*)wtp)[64 + lane] = z;
    *(uint4*)&vtp[lane * VTS + 24] = z;
  }

  // stage V transposed: vt[dim][key] (rows 0..23 of the band)
#pragma unroll
  for (int i = 0; i < 3; ++i) {
    int item = i * 64 + lane;
    int row = item >> 3, chb = (item & 7) * 8;
    int pos = p0 + row;
    uint4 vv = make_uint4(0, 0, 0, 0);
    if (pos >= 0) vv = *(const uint4*)(V + headoff + (size_t)pos * DM + chb);
    union { uint4 v; _Float16 hh[8]; } u; u.v = vv;
#pragma unroll
    for (int d = 0; d < 8; ++d) vtp[(chb + d) * VTS + row] = u.hh[d];
  }

  // Q fragments straight from global (rows always valid)
  const _Float16* qrow = Q + headoff + (size_t)(s0 + wid * 16 + fm) * DM;
  h8v aq0 = *(const h8v*)(qrow + fkg);
  h8v aq1 = *(const h8v*)(qrow + 32 + fkg);

  // ---- QK^T: 2 local key-tiles x K=64, K-frags DIRECT from global ----
  f32x4 accs[2] = {};
#pragma unroll
  for (int t = 0; t < 2; ++t) {
    int pos = p0 + t * 16 + fm;
    int pc = pos < 0 ? 0 : (pos > S_LEN - 1 ? S_LEN - 1 : pos);
    const _Float16* krow = K + headoff + (size_t)pc * DM;
    h8v bk0 = *(const h8v*)(krow + fkg);
    h8v bk1 = *(const h8v*)(krow + 32 + fkg);
    accs[t] = __builtin_amdgcn_mfma_f32_16x16x32_f16(aq0, bk0, accs[t], 0, 0, 0);
    accs[t] = __builtin_amdgcn_mfma_f32_16x16x32_f16(aq1, bk1, accs[t], 0, 0, 0);
  }
#pragma unroll
  for (int t = 0; t < 2; ++t)
#pragma unroll
    for (int r = 0; r < 4; ++r)
      scp[(rr + r) * 33 + t * 16 + cc] = accs[t][r];

  // ---- softmax: lane r (0..15) owns q-row r; band cols r..r+8 (< 24) ----
  if (lane < 16) {
    int r = lane, s = s0 + wid * 16 + r;
    const float* my = &scp[r * 33 + r];
    float e[9], mx = -1e30f;
#pragma unroll
    for (int j = 0; j < 9; ++j) {
      float p = my[j] * INV2T;
      e[j] = (s - RAD + j >= 0) ? p : -1e30f;
      mx = fmaxf(mx, e[j]);
    }
    float se = 0.f;
#pragma unroll
    for (int j = 0; j < 9; ++j) { e[j] = __expf(e[j] - mx); se += e[j]; }
    float inv = 1.f / se;
#pragma unroll
    for (int j = 0; j < 9; ++j)
      wtp[r * WS + r + j] = (_Float16)(e[j] * inv);
  }

  // ---- PV: O(16x64) = wt(16x32) @ V(32x64); one K=32 MFMA per n-tile ----
  f32x4 acco[4] = {};
  h8v aw = *(const h8v*)&wtp[fm * WS + fkg];
#pragma unroll
  for (int t = 0; t < 4; ++t) {
    h8v bv = *(const h8v*)&vtp[(t * 16 + fm) * VTS + fkg];
    acco[t] = __builtin_amdgcn_mfma_f32_16x16x32_f16(aw, bv, acco[t], 0, 0, 0);
  }
#pragma unroll
  for (int t = 0; t < 4; ++t)
#pragma unroll
    for (int r = 0; r < 4; ++r)
      O[headoff + (size_t)(s0 + wid * 16 + rr + r) * DM + t * 16 + cc] =
          (_Float16)acco[t][r];
}

extern "C" void kernel_launch(void* const* d_in, const int* in_sizes, int n_in,
                              void* d_out, int out_size, void* d_ws, size_t ws_size,
                              hipStream_t stream) {
  (void)in_sizes; (void)n_in; (void)out_size; (void)ws_size;
  const float* x  = (const float*)d_in[0];
  const float* Wq = (const float*)d_in[1];
  const float* Wk = (const float*)d_in[2];
  const float* Wv = (const float*)d_in[3];
  const float* Wo = (const float*)d_in[4];

  char* ws = (char*)d_ws;
  const size_t MB = 1ull << 20;
  _Float16* xh    = (_Float16*)(ws + 0);        // 16 MB
  _Float16* WqkvT = (_Float16*)(ws + 16 * MB);  // 6 MB: Wq^T|Wk^T|Wv^T
  _Float16* WoT   = (_Float16*)(ws + 22 * MB);  // 2 MB
  _Float16* Qh    = (_Float16*)(ws + 24 * MB);  // 16 MB each
  _Float16* Kh    = (_Float16*)(ws + 40 * MB);
  _Float16* Vh    = (_Float16*)(ws + 56 * MB);
  _Float16* Ah    = (_Float16*)(ws + 72 * MB);  // total 88 MB

  sda_prep_kernel<<<dim3(32, 32, 8), dim3(32, 8), 0, stream>>>(
      x, xh, Wq, Wk, Wv, Wo,
      WqkvT, WqkvT + (size_t)DM * DM, WqkvT + 2ull * DM * DM, WoT);

  // QKV fused: M=8192, N=3072 -> 1536 blocks (1D, XCD-swizzled)
  sda_gemm_qkv_kernel<<<1536, 256, 0, stream>>>(xh, WqkvT, Qh, Kh, Vh);
  sda_attn_kernel<<<dim3(64, 32), 256, 0, stream>>>(Qh, Kh, Vh, Ah);
  // Wo: 128x128 -> 512 blocks
  sda_gemm_wo_kernel<<<512, 256, 0, stream>>>(Ah, WoT, (float*)d_out);
}